// Round 14
// baseline (308.960 us; speedup 1.0000x reference)
//
#include <hip/hip_runtime.h>
#include <hip/hip_bf16.h>

typedef __bf16 bf16;
typedef __bf16 bf16x8 __attribute__((ext_vector_type(8)));
typedef __bf16 bf16x4 __attribute__((ext_vector_type(4)));
typedef float f32x4 __attribute__((ext_vector_type(4)));

// ---------------------------------------------------------------------------
// Shapes: H=8, CH=32, S=256, NR=256, C=128, M = NR*S = 65536
// Fragment facts (validated R2..R13 passes):
//   mfma_f32_16x16x32_bf16: A row=lane&15,k=8g+i ; B col=lane&15,k=8g+i ;
//                           D col=lane&15, row=4g+j   (learn_hip m89)
// R14: projections/out_proj recomputed in TRANSPOSED orientation
//   mfma(A=W^T rows n, B=X col m) -> D col=m (lane-local), row=n=4g+j
//   -> every epilogue store is an 8B/16B vector op. attn unchanged (R13).
// perm(ch) = ((ch>>2)&3)*8 + ((ch>>4)&1)*4 + (ch&3)   (G/Og channel order)
// K image:  elem (t,ch) at t*32 + (((ch>>3) ^ ((t>>1)&3))<<3) + (ch&7)
// V image:  elem (ch,t) at ((t>>2)*32 + (ch ^ ((t>>2)&7)))*4 + (t&3)
// ---------------------------------------------------------------------------

#define M_TOT 65536
#define LOG2E 1.4426950408889634f
#define QSCALE 0.2550348652402226f     // 1/sqrt(32) * log2e

static __device__ __forceinline__ f32x4 mfma32(bf16x8 a, bf16x8 b, f32x4 c) {
    return __builtin_amdgcn_mfma_f32_16x16x32_bf16(a, b, c, 0, 0, 0);
}

static __device__ __forceinline__ float exp2_(float x) {
#if __has_builtin(__builtin_amdgcn_exp2f)
    return __builtin_amdgcn_exp2f(x);
#else
    return exp2f(x);
#endif
}

// async 16B/lane global->LDS: lds dest = uniform base + lane*16 (HW rule)
static __device__ __forceinline__ void g2lds16(bf16* lds_base, const bf16* g_lane) {
#if __has_builtin(__builtin_amdgcn_global_load_lds)
    __builtin_amdgcn_global_load_lds(
        (const __attribute__((address_space(1))) void*)g_lane,
        (__attribute__((address_space(3))) void*)lds_base, 16, 0, 0);
#else
    int lane = threadIdx.x & 63;
    *(bf16x8*)(lds_base + lane * 8) = *(const bf16x8*)g_lane;
#endif
}

static __device__ __forceinline__ int permch(int ch) {
    return ((ch >> 2) & 3) * 8 + ((ch >> 4) & 1) * 4 + (ch & 3);
}

// ---------------- prep: weight transposes + scaled biases ------------------
__global__ void wprep_kernel(const float* __restrict__ wq, const float* __restrict__ wk,
                             const float* __restrict__ wv, const float* __restrict__ wg,
                             const float* __restrict__ wo, bf16* __restrict__ Wt,
                             const float* __restrict__ bp, bf16* __restrict__ bpb,
                             const float* __restrict__ bm, float* __restrict__ bms)
{
    int job = blockIdx.y;
    int idx = blockIdx.x * 256 + threadIdx.x;   // 0..32767 (grid.x = 128)
    if (job == 5) {
        for (int i = idx; i < 8 * 256 * 256; i += 32768)
            bpb[i] = (bf16)(bp[i] * LOG2E);
        return;
    }
    if (job == 6) {
        for (int i = idx; i < 65536; i += 32768)
            bms[i] = bm[i] * LOG2E;
        return;
    }
    if (job == 4) {
        // woT with permuted k index (cancels attn's permuted Og layout)
        int n = idx >> 8, k = idx & 255;        // n: out 0..127, k: in 0..255
        int h = k >> 5, ch = k & 31;
        Wt[4 * 32768 + n * 256 + h * 32 + permch(ch)] = (bf16)wo[k * 128 + n];
        return;
    }
    const float* src;
    switch (job) {
        case 0: src = wq; break;
        case 1: src = wk; break;
        case 2: src = wv; break;
        default: src = wg; break;
    }
    bf16* dst = Wt + job * 32768;
    int n = idx >> 7, k = idx & 127;            // K=128, N=256
    dst[idx] = (bf16)src[k * 256 + n];          // dst[n][k] = src[k][n]
}

// ---------------- Q + G projection (transposed, no LDS) --------------------
// Wave owns 16 m rows; D col = m. Q -> [h][m][32] (true ch order, 8B stores);
// G -> [h][m][perm] (8B stores).
__global__ __launch_bounds__(256, 4)
void proj_qg_kernel(const float* __restrict__ X, const bf16* __restrict__ WqT,
                    const bf16* __restrict__ WgT, const float* __restrict__ bg,
                    bf16* __restrict__ Q, bf16* __restrict__ G)
{
    const int tid = threadIdx.x;
    const int lane = tid & 63, w = tid >> 6;
    const int c = lane & 15, g = lane >> 4;
    const int m = blockIdx.x * 64 + w * 16 + c;      // lane-owned row
    const f32x4 fzero = {0.f, 0.f, 0.f, 0.f};

    // own X row -> bf16 B-frags (registers; each lane distinct 32B/kk)
    bf16x8 xb[4];
    {
        const float* src = X + (size_t)m * 128;
#pragma unroll
        for (int kk = 0; kk < 4; ++kk) {
            float4 a = *(const float4*)(src + kk * 32 + g * 8);
            float4 b = *(const float4*)(src + kk * 32 + g * 8 + 4);
            bf16x8 v;
            v[0] = (bf16)a.x; v[1] = (bf16)a.y; v[2] = (bf16)a.z; v[3] = (bf16)a.w;
            v[4] = (bf16)b.x; v[5] = (bf16)b.y; v[6] = (bf16)b.z; v[7] = (bf16)b.w;
            xb[kk] = v;
        }
    }

    // ---- Q ----
    {
        f32x4 acc[16];
#pragma unroll
        for (int i = 0; i < 16; ++i) acc[i] = fzero;
#pragma unroll
        for (int kk = 0; kk < 4; ++kk)
#pragma unroll
            for (int nt = 0; nt < 16; ++nt) {
                bf16x8 wa = *(const bf16x8*)(WqT + (size_t)(nt * 16 + c) * 128 + kk * 32 + g * 8);
                acc[nt] = mfma32(wa, xb[kk], acc[nt]);
            }
#pragma unroll
        for (int nt = 0; nt < 16; ++nt) {
            int h = nt >> 1, r = nt & 1;        // n = nt*16+4g+j, ch = r*16+4g+j
            bf16x4 pk;
#pragma unroll
            for (int j = 0; j < 4; ++j) pk[j] = (bf16)(acc[nt][j] * QSCALE);
            *(bf16x4*)(Q + ((size_t)h * M_TOT + m) * 32 + r * 16 + 4 * g) = pk;
        }
    }
    // ---- G ----
    {
        f32x4 acc[16];
#pragma unroll
        for (int i = 0; i < 16; ++i) acc[i] = fzero;
#pragma unroll
        for (int kk = 0; kk < 4; ++kk)
#pragma unroll
            for (int nt = 0; nt < 16; ++nt) {
                bf16x8 wa = *(const bf16x8*)(WgT + (size_t)(nt * 16 + c) * 128 + kk * 32 + g * 8);
                acc[nt] = mfma32(wa, xb[kk], acc[nt]);
            }
#pragma unroll
        for (int nt = 0; nt < 16; ++nt) {
            int h = nt >> 1, r = nt & 1;
            f32x4 b4 = *(const f32x4*)(bg + nt * 16 + 4 * g);
            bf16x4 pk;                          // perm(r*16+4g+j) = g*8+r*4+j
#pragma unroll
            for (int j = 0; j < 4; ++j)
                pk[j] = (bf16)(1.f / (1.f + __expf(-(acc[nt][j] + b4[j]))));
            *(bf16x4*)(G + ((size_t)h * M_TOT + m) * 32 + g * 8 + r * 4) = pk;
        }
    }
}

// ---------------- K + V projection -> swizzled images ----------------------
// K: transposed orientation (D col = t) -> 8B stores into K image.
// V: original orientation (D row = t, fastest in image) -> 8B stores.
__global__ __launch_bounds__(256, 4)
void proj_kv_kernel(const float* __restrict__ X, const bf16* __restrict__ WkT,
                    const bf16* __restrict__ WvT, bf16* __restrict__ Kimg,
                    bf16* __restrict__ Vimg)
{
    __shared__ bf16 Xs[64][136];                // +8 pad -> 2-way banks
    const int tid = threadIdx.x;
    const int mbase = blockIdx.x * 64;

    for (int i = tid; i < 2048; i += 256) {     // 64x128 fp32 -> bf16
        int mm = i >> 5;
        int k4 = (i & 31) << 2;
        float4 v = *(const float4*)(X + (size_t)(mbase + mm) * 128 + k4);
        bf16x4 pk;
        pk.x = (bf16)v.x; pk.y = (bf16)v.y; pk.z = (bf16)v.z; pk.w = (bf16)v.w;
        *(bf16x4*)&Xs[mm][k4] = pk;
    }
    __syncthreads();

    const int lane = tid & 63, w = tid >> 6;
    const int c = lane & 15, g = lane >> 4;
    const f32x4 fzero = {0.f, 0.f, 0.f, 0.f};

    // ---- K (transposed; wave owns rows w*16..+16) --------------------------
    {
        bf16x8 xbK[4];
#pragma unroll
        for (int kk = 0; kk < 4; ++kk)
            xbK[kk] = *(const bf16x8*)&Xs[w * 16 + c][kk * 32 + g * 8];
        f32x4 acc[16];
#pragma unroll
        for (int i = 0; i < 16; ++i) acc[i] = fzero;
#pragma unroll
        for (int kk = 0; kk < 4; ++kk)
#pragma unroll
            for (int nt = 0; nt < 16; ++nt) {
                bf16x8 wa = *(const bf16x8*)(WkT + (size_t)(nt * 16 + c) * 128 + kk * 32 + g * 8);
                acc[nt] = mfma32(wa, xbK[kk], acc[nt]);
            }
        const int m = mbase + w * 16 + c;
        const int nr = m >> 8, t = m & 255;
        const int tsw = (t >> 1) & 3;
#pragma unroll
        for (int nt = 0; nt < 16; ++nt) {
            int h = nt >> 1, r = nt & 1;        // ch = 16r+4g+j
            int c4 = 2 * r + (g >> 1);          // ch>>3 ; ch&7 = 4(g&1)+j
            bf16x4 pk;
#pragma unroll
            for (int j = 0; j < 4; ++j) pk[j] = (bf16)acc[nt][j];
            *(bf16x4*)&Kimg[(size_t)(h * 256 + nr) * 8192 + t * 32 +
                            ((c4 ^ tsw) << 3) + 4 * (g & 1)] = pk;
        }
    }

    // ---- V (original; wave owns 64 ch cols nstrip = w*64) ------------------
    {
        const int nstrip = w * 64;
        f32x4 acc[4][4];
#pragma unroll
        for (int a = 0; a < 4; ++a)
#pragma unroll
            for (int b = 0; b < 4; ++b) acc[a][b] = fzero;
#pragma unroll
        for (int kk = 0; kk < 4; ++kk) {
            bf16x8 af[4], bfr[4];
#pragma unroll
            for (int mi = 0; mi < 4; ++mi)
                af[mi] = *(const bf16x8*)&Xs[mi * 16 + c][kk * 32 + g * 8];
#pragma unroll
            for (int ni = 0; ni < 4; ++ni)
                bfr[ni] = *(const bf16x8*)(WvT + (size_t)(nstrip + ni * 16 + c) * 128 + kk * 32 + g * 8);
#pragma unroll
            for (int mi = 0; mi < 4; ++mi)
#pragma unroll
                for (int ni = 0; ni < 4; ++ni)
                    acc[mi][ni] = mfma32(af[mi], bfr[ni], acc[mi][ni]);
        }
#pragma unroll
        for (int mi = 0; mi < 4; ++mi)
#pragma unroll
            for (int ni = 0; ni < 4; ++ni) {
                int n = nstrip + ni * 16 + c;
                int h = n >> 5, ch = n & 31;
                int m0 = mbase + mi * 16 + g * 4;   // 4 consecutive t
                int nr = m0 >> 8, t0 = m0 & 255;
                int tg = t0 >> 2;
                bf16x4 pk;
#pragma unroll
                for (int j = 0; j < 4; ++j) pk[j] = (bf16)acc[mi][ni][j];
                *(bf16x4*)&Vimg[(size_t)(h * 256 + nr) * 8192 + (tg * 32 + (ch ^ (tg & 7))) * 4] = pk;
            }
    }
}

// ---------------- fused attention (R13 verbatim) ----------------------------
__global__ __launch_bounds__(256, 4)
void attn_kernel(const bf16* __restrict__ Q, const bf16* __restrict__ Kimg,
                 const bf16* __restrict__ Vimg, const bf16* __restrict__ G,
                 const float* __restrict__ bms, const bf16* __restrict__ bpb,
                 bf16* __restrict__ Og)
{
    __shared__ bf16 Ks[8192];       // 16 KB, K image (already swizzled)
    __shared__ bf16 Vs[8192];       // 16 KB, V image (already swizzled)
    __shared__ float bms_s[256];    //  1 KB

    const int h = blockIdx.x, nr = blockIdx.y;
    const int tid = threadIdx.x;
    const int lane = tid & 63, w = tid >> 6;
    const int c = lane & 15, g = lane >> 4;

    const bf16* Kslab = Kimg + (size_t)(h * 256 + nr) * 8192;
    const bf16* Vslab = Vimg + (size_t)(h * 256 + nr) * 8192;
#pragma unroll
    for (int r = 0; r < 4; ++r) {
        int off = (w * 4 + r) * 512;            // bf16 elems (1KB chunks)
        g2lds16(&Ks[off], Kslab + off + lane * 8);
        g2lds16(&Vs[off], Vslab + off + lane * 8);
    }
    bms_s[tid] = bms[nr * 256 + tid];
    __syncthreads();                            // drains vmcnt (incl. LDS-DMA)

    const bf16* Qh = Q + ((size_t)h * M_TOT + nr * 256) * 32;
    const bf16* Gh = G + ((size_t)h * M_TOT + nr * 256) * 32;
    bf16* Oh = Og + ((size_t)h * M_TOT + nr * 256) * 32;
    const bf16* bph = bpb + (size_t)h * 65536;
    const f32x4 fzero = {0.f, 0.f, 0.f, 0.f};
    const int kswz = (g ^ ((c >> 1) & 3)) << 3;

#pragma unroll
    for (int qc = 0; qc < 4; ++qc) {
        const int q = w * 64 + qc * 16 + c;
        bf16x8 bq = *(const bf16x8*)(Qh + (size_t)q * 32 + g * 8);
        bf16x8 gv8 = *(const bf16x8*)(Gh + (size_t)q * 32 + g * 8);
        const bf16* bpq = bph + (size_t)q * 256;
        bf16x4 bpv[16];
#pragma unroll
        for (int nt = 0; nt < 16; ++nt)
            bpv[nt] = *(const bf16x4*)(bpq + nt * 16 + 4 * g);

        f32x4 s[16];
#pragma unroll
        for (int nt = 0; nt < 16; ++nt) {
            f32x4 cin = *(const f32x4*)&bms_s[nt * 16 + 4 * g];
#pragma unroll
            for (int j = 0; j < 4; ++j) cin[j] += (float)bpv[nt][j];
            bf16x8 ak = *(const bf16x8*)&Ks[(nt * 16 + c) * 32 + kswz];
            s[nt] = mfma32(ak, bq, cin);
        }

        float rs0 = 0.f, rs1 = 0.f, rs2 = 0.f, rs3 = 0.f;
#pragma unroll
        for (int nt = 0; nt < 16; ++nt) {
            float p0 = exp2_(s[nt][0]), p1 = exp2_(s[nt][1]);
            float p2 = exp2_(s[nt][2]), p3 = exp2_(s[nt][3]);
            s[nt][0] = p0; s[nt][1] = p1; s[nt][2] = p2; s[nt][3] = p3;
            rs0 += p0; rs1 += p1; rs2 += p2; rs3 += p3;
        }
        float rs = (rs0 + rs1) + (rs2 + rs3);
        rs += __shfl_xor(rs, 16);
        rs += __shfl_xor(rs, 32);
        float rinv = 1.f / rs;

        f32x4 o[2] = {fzero, fzero};
#pragma unroll
        for (int p2 = 0; p2 < 8; ++p2) {
            bf16x8 pb;
#pragma unroll
            for (int j = 0; j < 4; ++j) {
                pb[j]     = (bf16)s[2 * p2][j];
                pb[4 + j] = (bf16)s[2 * p2 + 1][j];
            }
            const int tg0 = 8 * p2 + g;
            const int tg1 = 8 * p2 + 4 + g;
#pragma unroll
            for (int cc = 0; cc < 2; ++cc) {
                bf16x4 a0 = *(const bf16x4*)&Vs[(tg0 * 32 + ((cc * 16 + c) ^ (tg0 & 7))) * 4];
                bf16x4 a1 = *(const bf16x4*)&Vs[(tg1 * 32 + ((cc * 16 + c) ^ (tg1 & 7))) * 4];
                bf16x8 av = {a0[0], a0[1], a0[2], a0[3], a1[0], a1[1], a1[2], a1[3]};
                o[cc] = mfma32(av, pb, o[cc]);
            }
        }

        bf16x8 ov8;
#pragma unroll
        for (int cc = 0; cc < 2; ++cc)
#pragma unroll
            for (int j = 0; j < 4; ++j)
                ov8[cc * 4 + j] = (bf16)(o[cc][j] * rinv * (float)gv8[cc * 4 + j]);
        *(bf16x8*)(Oh + (size_t)q * 32 + g * 8) = ov8;
    }
}

// ---------------- output projection (transposed, no LDS) -------------------
// Og: [8][M][perm] ; woT: [128][256] (k permuted identically) -> cancellation.
// D col = m -> float4 stores (full 64B lines per instr).
__global__ __launch_bounds__(256, 4)
void out_proj_kernel(const bf16* __restrict__ Og, const bf16* __restrict__ woT,
                     const float* __restrict__ bo, float* __restrict__ out)
{
    const int tid = threadIdx.x;
    const int lane = tid & 63, w = tid >> 6;
    const int c = lane & 15, g = lane >> 4;
    const int m = blockIdx.x * 64 + w * 16 + c;      // lane-owned row
    const f32x4 fzero = {0.f, 0.f, 0.f, 0.f};

    f32x4 acc[8];
#pragma unroll
    for (int i = 0; i < 8; ++i) acc[i] = fzero;

#pragma unroll
    for (int kk = 0; kk < 8; ++kk) {                 // kk = head
        bf16x8 ob = *(const bf16x8*)(Og + ((size_t)kk * M_TOT + m) * 32 + g * 8);
#pragma unroll
        for (int nt = 0; nt < 8; ++nt) {
            bf16x8 wa = *(const bf16x8*)(woT + (size_t)(nt * 16 + c) * 256 + kk * 32 + g * 8);
            acc[nt] = mfma32(wa, ob, acc[nt]);
        }
    }

#pragma unroll
    for (int nt = 0; nt < 8; ++nt) {                 // n = nt*16 + 4g + j
        f32x4 b4 = *(const f32x4*)(bo + nt * 16 + 4 * g);
        f32x4 vout;
#pragma unroll
        for (int j = 0; j < 4; ++j) vout[j] = acc[nt][j] + b4[j];
        *(f32x4*)(out + (size_t)m * 128 + nt * 16 + 4 * g) = vout;
    }
}

// ---------------------------------------------------------------------------
extern "C" void kernel_launch(void* const* d_in, const int* in_sizes, int n_in,
                              void* d_out, int out_size, void* d_ws, size_t ws_size,
                              hipStream_t stream)
{
    const float* q_x       = (const float*)d_in[0];
    const float* kv_x      = (const float*)d_in[1];
    const float* bias_mask = (const float*)d_in[2];
    const float* bias_pair = (const float*)d_in[3];
    const float* wq        = (const float*)d_in[4];
    const float* wk        = (const float*)d_in[5];
    const float* wv        = (const float*)d_in[6];
    const float* wg        = (const float*)d_in[7];
    const float* bg        = (const float*)d_in[8];
    const float* wo        = (const float*)d_in[9];
    const float* bo        = (const float*)d_in[10];
    float* out = (float*)d_out;

    char* ws = (char*)d_ws;
    const size_t MB = 1024ull * 1024ull;
    bf16*  Qb  = (bf16*)(ws);                    // [8][65536][32]
    bf16*  Kb  = (bf16*)(ws + 32 * MB);          // K images [2048][8192]
    bf16*  Gb  = (bf16*)(ws + 64 * MB);          // [8][65536][perm]
    bf16*  Vtb = (bf16*)(ws + 96 * MB);          // V images [2048][8192]
    bf16*  Ogb = (bf16*)(ws + 128 * MB);         // [8][65536][perm]
    bf16*  Wt  = (bf16*)(ws + 160 * MB);         // 5 x 32768 bf16 (320 KB)
    bf16*  bpb = (bf16*)(ws + 160 * MB + 512 * 1024);    // [8][256][256] bf16
    float* bms = (float*)(ws + 160 * MB + 2560 * 1024);  // [256][256] f32

    wprep_kernel<<<dim3(128, 7), 256, 0, stream>>>(wq, wk, wv, wg, wo, Wt,
                                                   bias_pair, bpb, bias_mask, bms);

    proj_qg_kernel<<<dim3(1024), 256, 0, stream>>>(q_x, Wt, Wt + 3 * 32768,
                                                   bg, Qb, Gb);
    proj_kv_kernel<<<dim3(1024), 256, 0, stream>>>(kv_x, Wt + 1 * 32768,
                                                   Wt + 2 * 32768, Kb, Vtb);

    attn_kernel<<<dim3(8, 256), 256, 0, stream>>>(Qb, Kb, Vtb, Gb, bms, bpb, Ogb);

    out_proj_kernel<<<dim3(1024), 256, 0, stream>>>(Ogb, Wt + 4 * 32768, bo, out);
}